// Round 1
// baseline (55850.171 us; speedup 1.0000x reference)
//
#include <hip/hip_runtime.h>
#include <hip/hip_cooperative_groups.h>
#include <math.h>

namespace cg = cooperative_groups;

#define B_ 64
#define T_ 512
#define F_ 128
#define H_ 512

// ---------------------------------------------------------------------------
// One-time input transpose: input[b][t][f] -> xT[t][f][b]
// so per-step layer-0 loads are coalesced over the batch dim (lane = b).
// ---------------------------------------------------------------------------
__global__ void transpose_x(const float* __restrict__ in, float* __restrict__ xT) {
    __shared__ float tile[F_][B_ + 1];   // +1 pad: no LDS bank conflicts
    const int t   = blockIdx.x;
    const int tid = threadIdx.x;
    for (int idx = tid; idx < B_ * F_; idx += blockDim.x) {
        int bb = idx >> 7;          // / F_
        int f  = idx & (F_ - 1);
        tile[f][bb] = in[(size_t)bb * T_ * F_ + (size_t)t * F_ + f]; // coalesced over f
    }
    __syncthreads();
    for (int idx = tid; idx < B_ * F_; idx += blockDim.x) {
        int f  = idx >> 6;          // / B_
        int bb = idx & (B_ - 1);
        xT[(size_t)t * F_ * B_ + (size_t)f * B_ + bb] = tile[f][bb]; // coalesced over b
    }
}

__device__ __forceinline__ float sigmoid_(float x) { return 1.0f / (1.0f + expf(-x)); }

// ---------------------------------------------------------------------------
// Persistent layer-pipelined LSTM scan.
// Grid = 384 blocks x 256 threads. Block (layer = bid>>7, cb = bid&127) owns
// state columns [cb*4, cb*4+4) of `layer`. Thread (b = tid&63, j = tid>>6)
// computes the 4 gate pre-activations for (b, sc = cb*4 + j); c-state is one
// register per thread. Global step s: layer l processes t = s - l.
// h buffers double-buffered by parity t&1; one grid.sync per step.
// ---------------------------------------------------------------------------
__global__ void lstm_scan(
    const float* __restrict__ xT, float* __restrict__ hb, float* __restrict__ h1s,
    float* __restrict__ out,
    const float* __restrict__ Wih0, const float* __restrict__ Whh0,
    const float* __restrict__ bih0, const float* __restrict__ bhh0,
    const float* __restrict__ Wih1, const float* __restrict__ Whh1,
    const float* __restrict__ bih1, const float* __restrict__ bhh1,
    const float* __restrict__ Wih2, const float* __restrict__ Whh2,
    const float* __restrict__ bih2, const float* __restrict__ bhh2,
    const float* __restrict__ fcW1, const float* __restrict__ fcb1,
    const float* __restrict__ fcW2, const float* __restrict__ fcb2) {
    cg::grid_group grid = cg::this_grid();

    const float* WihA[3] = {Wih0, Wih1, Wih2};
    const float* WhhA[3] = {Whh0, Whh1, Whh2};
    const float* bihA[3] = {bih0, bih1, bih2};
    const float* bhhA[3] = {bhh0, bhh1, bhh2};

    const int layer = blockIdx.x >> 7;       // 0..2
    const int cb    = blockIdx.x & 127;      // 0..127
    const int b     = threadIdx.x & 63;      // lane = batch row
    // j is uniform across each wave (wave = 64 consecutive tids); force scalar.
    const int j  = __builtin_amdgcn_readfirstlane((int)(threadIdx.x >> 6)); // 0..3
    const int sc = cb * 4 + j;               // owned state column
    const int Kx = (layer == 0) ? F_ : H_;   // input-stream dot length

    const float* wih = WihA[layer];
    const float* whh = WhhA[layer];
    const size_t r0 = (size_t)sc, r1 = (size_t)sc + 512,
                 r2 = (size_t)sc + 1024, r3 = (size_t)sc + 1536;
    // Gate order i,f,g,o (PyTorch). Fold both biases once.
    const float bias0 = bihA[layer][r0] + bhhA[layer][r0];
    const float bias1 = bihA[layer][r1] + bhhA[layer][r1];
    const float bias2 = bihA[layer][r2] + bhhA[layer][r2];
    const float bias3 = bihA[layer][r3] + bhhA[layer][r3];
    // Wave-uniform W row pointers -> scalar loads in the dot loops.
    const float* wx0 = wih + r0 * (size_t)Kx;
    const float* wx1 = wih + r1 * (size_t)Kx;
    const float* wx2 = wih + r2 * (size_t)Kx;
    const float* wx3 = wih + r3 * (size_t)Kx;
    const float* wh0 = whh + r0 * (size_t)H_;
    const float* wh1 = whh + r1 * (size_t)H_;
    const float* wh2 = whh + r2 * (size_t)H_;
    const float* wh3 = whh + r3 * (size_t)H_;

    float* hb_l = hb + (size_t)layer * 2 * H_ * B_;            // this layer's 2 parities
    const float* hb_in = (layer == 0) ? xT
                         : hb + (size_t)(layer - 1) * 2 * H_ * B_;

    float c_reg = 0.0f;

    for (int s = 0; s < T_ + 2; ++s) {
        const int t = s - layer;
        if (t >= 0 && t < T_) {
            const int p_out  = t & 1;        // write parity; also input-stream parity
            const int p_prev = (t + 1) & 1;  // h(t-1) parity (zeros at t=0 via memset)
            const float* xs = (layer == 0)
                                  ? (xT + (size_t)t * F_ * B_)
                                  : (hb_in + (size_t)p_out * H_ * B_);
            const float* hp = hb_l + (size_t)p_prev * H_ * B_;

            float a0 = bias0, a1 = bias1, a2 = bias2, a3 = bias3;
#pragma unroll 8
            for (int k = 0; k < Kx; ++k) {       // input-stream dot
                const float xv = xs[(size_t)k * B_ + b];   // 256B coalesced per wave
                a0 = fmaf(wx0[k], xv, a0);
                a1 = fmaf(wx1[k], xv, a1);
                a2 = fmaf(wx2[k], xv, a2);
                a3 = fmaf(wx3[k], xv, a3);
            }
#pragma unroll 8
            for (int k = 0; k < H_; ++k) {       // recurrent dot
                const float hv = hp[(size_t)k * B_ + b];
                a0 = fmaf(wh0[k], hv, a0);
                a1 = fmaf(wh1[k], hv, a1);
                a2 = fmaf(wh2[k], hv, a2);
                a3 = fmaf(wh3[k], hv, a3);
            }
            const float ig = sigmoid_(a0);
            const float fg = sigmoid_(a1);
            const float gg = tanhf(a2);
            const float og = sigmoid_(a3);
            c_reg = fg * c_reg + ig * gg;
            const float hv = og * tanhf(c_reg);
            hb_l[(size_t)p_out * H_ * B_ + (size_t)sc * B_ + b] = hv;
        }
        grid.sync();
    }

    // ---- FC head: h1 = relu(h2(511) @ fcW1^T + fcb1); out = relu(h1 @ fcW2^T + fcb2)
    const float* h2 = hb + (size_t)(2 * 2 + 1) * H_ * B_;  // layer 2, parity 511&1 = 1
    if (blockIdx.x < 64 && threadIdx.x < 64) {
        const int c  = blockIdx.x;
        const int bb = threadIdx.x;
        float acc = fcb1[c];
#pragma unroll 8
        for (int k = 0; k < H_; ++k)
            acc = fmaf(fcW1[(size_t)c * H_ + k], h2[(size_t)k * B_ + bb], acc);
        h1s[c * B_ + bb] = fmaxf(acc, 0.0f);
    }
    grid.sync();
    if (blockIdx.x == 0 && threadIdx.x < 64) {
        const int bb = threadIdx.x;
        float acc = fcb2[0];
#pragma unroll
        for (int c = 0; c < 64; ++c)
            acc = fmaf(fcW2[c], h1s[c * B_ + bb], acc);
        out[bb] = fmaxf(acc, 0.0f);
    }
}

// ---------------------------------------------------------------------------
extern "C" void kernel_launch(void* const* d_in, const int* in_sizes, int n_in,
                              void* d_out, int out_size, void* d_ws, size_t ws_size,
                              hipStream_t stream) {
    const float* in    = (const float*)d_in[0];
    const float* Wih0  = (const float*)d_in[1];
    const float* Whh0  = (const float*)d_in[2];
    const float* bih0  = (const float*)d_in[3];
    const float* bhh0  = (const float*)d_in[4];
    const float* Wih1  = (const float*)d_in[5];
    const float* Whh1  = (const float*)d_in[6];
    const float* bih1  = (const float*)d_in[7];
    const float* bhh1  = (const float*)d_in[8];
    const float* Wih2  = (const float*)d_in[9];
    const float* Whh2  = (const float*)d_in[10];
    const float* bih2  = (const float*)d_in[11];
    const float* bhh2  = (const float*)d_in[12];
    const float* fcW1  = (const float*)d_in[13];
    const float* fcb1  = (const float*)d_in[14];
    const float* fcW2  = (const float*)d_in[15];
    const float* fcb2  = (const float*)d_in[16];
    float* outp = (float*)d_out;

    float* ws  = (float*)d_ws;
    float* xT  = ws;                                   // [T][F][B]  = 4,194,304 f
    float* hbf = xT + (size_t)T_ * F_ * B_;            // [3][2][H][B] = 196,608 f
    float* h1s = hbf + (size_t)3 * 2 * H_ * B_;        // [64][64]   = 4,096 f

    // h buffers must start at zero (h(-1) = c(-1) = 0); ws is poisoned each call.
    hipMemsetAsync(hbf, 0, (size_t)3 * 2 * H_ * B_ * sizeof(float), stream);

    transpose_x<<<dim3(T_), dim3(256), 0, stream>>>(in, xT);

    void* args[] = {
        (void*)&xT, (void*)&hbf, (void*)&h1s, (void*)&outp,
        (void*)&Wih0, (void*)&Whh0, (void*)&bih0, (void*)&bhh0,
        (void*)&Wih1, (void*)&Whh1, (void*)&bih1, (void*)&bhh1,
        (void*)&Wih2, (void*)&Whh2, (void*)&bih2, (void*)&bhh2,
        (void*)&fcW1, (void*)&fcb1, (void*)&fcW2, (void*)&fcb2};
    hipLaunchCooperativeKernel((void*)lstm_scan, dim3(384), dim3(256), args, 0, stream);
}